// Round 5
// baseline (683.242 us; speedup 1.0000x reference)
//
#include <hip/hip_runtime.h>

// Problem constants (fixed by reference: seq (16,4096,1024) fp32, prune 0.5)
#define BATCH 16
#define NTOK  4096
#define DIM   1024
#define KSEL  2048                       // kept tokens
#define NPRUNE 2048                      // pruned tokens

#define NBIN 4096                        // 12-bit counting-sort bins
#define RTHREADS 1024
#define RBLK 4                           // rank blocks per batch
#define TPT (NTOK / RTHREADS)            // 4 tokens/thread (hist/scatter)
#define BPT (NBIN / RTHREADS)            // 4 bins/thread (scan)

#define GROWS 32                         // rows per gather block (128 KB)
#define GBLK (NTOK / GROWS)              // 128 gather blocks per batch

#define SCALE ((float)(0.05 / (2048.0 + 1e-10)))

typedef __attribute__((ext_vector_type(4))) float f32x4;

// ---------------------------------------------------------------------------
// Kernel 1: counting-sort rank -> rk[b][token] = rank.  (r2 structure —
// measured best across 5 rounds; r3/r4 deviations both regressed.)
// key(i) = (~sortable(w_i) << 32) | i  — ascending u64 order == jax.lax.top_k
// order (value desc, index asc). bin = top 12 bits. rank = bin base + exact
// within-bin count. grid (RBLK, BATCH): each block builds the full per-batch
// histogram/scan/scatter (O(N), duplicated, cheap) but ranks only a quarter
// of the tokens (1 token/thread). qq==0/t==0 also zeroes the per-batch
// fan-in counter used by the gather (workspace is harness-poisoned).
// ---------------------------------------------------------------------------
__global__ __launch_bounds__(1024) void rank_kernel(
    const float* __restrict__ w, int* __restrict__ rk,
    unsigned int* __restrict__ cnt) {
  __shared__ unsigned int s_cnt[NBIN];            // 16 KB histogram
  __shared__ unsigned int s_base[NBIN];           // 16 KB excl-scan bases
  __shared__ unsigned int s_cur[NBIN];            // 16 KB scatter cursors
  __shared__ unsigned long long s_key[NTOK];      // 32 KB keys grouped by bin
  __shared__ unsigned int s_wsum[16];
  __shared__ unsigned int s_woff[16];

  const int b = blockIdx.y;
  const int qq = blockIdx.x;                      // token quarter to rank
  const int t = threadIdx.x;
  const float* wb = w + (size_t)b * NTOK;

  if (qq == 0 && t == 0) cnt[b] = 0;              // visible at kernel boundary

  for (int i = t; i < NBIN; i += RTHREADS) s_cnt[i] = 0;
  __syncthreads();

  // load, keyify, histogram (all tokens of the batch)
  unsigned int inv[TPT];
  unsigned int bin[TPT];
#pragma unroll
  for (int p = 0; p < TPT; ++p) {
    const int j = p * RTHREADS + t;
    const unsigned int u = __float_as_uint(wb[j]);
    const unsigned int s = (u & 0x80000000u) ? ~u : (u | 0x80000000u);
    const unsigned int iv = ~s;                   // ascending iv == desc value
    inv[p] = iv; bin[p] = iv >> 20;
    atomicAdd(&s_cnt[bin[p]], 1u);
  }
  __syncthreads();

  // exclusive scan over 4096 bins: 4 bins/thread -> wave shfl scan -> combine
  unsigned int c[BPT];
  unsigned int lsum = 0;
#pragma unroll
  for (int i = 0; i < BPT; ++i) { c[i] = s_cnt[t * BPT + i]; lsum += c[i]; }
  const int lane = t & 63, wid = t >> 6;
  unsigned int v = lsum;
  for (int d = 1; d < 64; d <<= 1) {
    unsigned int up = __shfl_up(v, d, 64);
    if (lane >= d) v += up;
  }
  if (lane == 63) s_wsum[wid] = v;
  __syncthreads();
  if (t == 0) {
    unsigned int run = 0;
    for (int i = 0; i < 16; ++i) { const unsigned int x = s_wsum[i]; s_woff[i] = run; run += x; }
  }
  __syncthreads();
  unsigned int excl = v - lsum + s_woff[wid];
#pragma unroll
  for (int i = 0; i < BPT; ++i) {
    s_base[t * BPT + i] = excl;
    s_cur[t * BPT + i] = excl;
    excl += c[i];
  }
  __syncthreads();

  // scatter keys grouped by bin (arbitrary order within bin; rank is exact)
#pragma unroll
  for (int p = 0; p < TPT; ++p) {
    const int j = p * RTHREADS + t;
    const unsigned long long key =
        ((unsigned long long)inv[p] << 32) | (unsigned int)j;
    const unsigned int pos = atomicAdd(&s_cur[bin[p]], 1u);
    s_key[pos] = key;
  }
  __syncthreads();

  // exact rank for this block's quarter: 1 token/thread
  const int tok = qq * RTHREADS + t;
  const unsigned int u = __float_as_uint(wb[tok]);   // L1-hot reload
  const unsigned int s = (u & 0x80000000u) ? ~u : (u | 0x80000000u);
  const unsigned int iv = ~s;
  const unsigned long long key =
      ((unsigned long long)iv << 32) | (unsigned int)tok;
  const unsigned int bb = iv >> 20;
  const unsigned int st = s_base[bb];
  const unsigned int en = s_cur[bb];              // base + count
  unsigned int r = st;
  for (unsigned int q = st; q < en; ++q) r += (s_key[q] < key);
  rk[b * NTOK + tok] = (int)r;
}

// ---------------------------------------------------------------------------
// Kernel 2: streaming gather (r2 structure) + fan-in reduction. Reads seq
// PERFECTLY SEQUENTIALLY (each block: 32 consecutive rows = 128 KB,
// nontemporal), scatter-writes kept rows to out[rank] (fire-and-forget),
// accumulates pruned rows in-register, plain-stores one partial row per
// block (cached). Then release-fence + one counter atomicAdd per block; the
// LAST block of each batch acquire-fences, reduces the 128 partials, scales,
// and writes out[b][KSEL][:]. One counter atomic per block (128/batch) —
// none of r4's 2M data atomics. grid (GBLK, BATCH), block = 256.
// ---------------------------------------------------------------------------
__global__ __launch_bounds__(256) void gather_kernel(
    const float* __restrict__ seq, const int* __restrict__ rk,
    float* __restrict__ out, float* __restrict__ part,
    unsigned int* __restrict__ cnt) {
  __shared__ unsigned int s_last;
  const int b = blockIdx.y, g = blockIdx.x;
  const int lane = threadIdx.x;
  const f32x4* src = (const f32x4*)(seq + (size_t)b * NTOK * DIM) +
                     (size_t)g * GROWS * (DIM / 4);
  const int* rkb = rk + b * NTOK + g * GROWS;
  f32x4* outb = (f32x4*)(out + (size_t)b * (KSEL + 1) * DIM);
  f32x4 acc = {0.f, 0.f, 0.f, 0.f};
#pragma unroll 8
  for (int i = 0; i < GROWS; ++i) {
    const f32x4 x = __builtin_nontemporal_load(src + (size_t)i * (DIM / 4) + lane);
    const int r = rkb[i];                          // uniform -> scalar load
    if (r < KSEL) {
      __builtin_nontemporal_store(x, outb + (size_t)r * (DIM / 4) + lane);
    } else {
      acc += x;
    }
  }
  f32x4* pdst = (f32x4*)(part + ((size_t)b * GBLK + g) * DIM);
  pdst[lane] = acc;

  // fan-in: last arriving block of this batch reduces the partials
  __threadfence();                                 // release partial stores
  __syncthreads();
  if (lane == 0)
    s_last = (atomicAdd(&cnt[b], 1u) == GBLK - 1) ? 1u : 0u;
  __syncthreads();
  if (s_last) {
    __threadfence();                               // acquire others' partials
    const f32x4* p = (const f32x4*)(part + (size_t)b * GBLK * DIM);
    f32x4 a0 = {0.f, 0.f, 0.f, 0.f}, a1 = a0, a2 = a0, a3 = a0;
#pragma unroll
    for (int c0 = 0; c0 < GBLK; c0 += 4) {         // 4 independent chains (MLP)
      a0 += p[(size_t)(c0 + 0) * (DIM / 4) + lane];
      a1 += p[(size_t)(c0 + 1) * (DIM / 4) + lane];
      a2 += p[(size_t)(c0 + 2) * (DIM / 4) + lane];
      a3 += p[(size_t)(c0 + 3) * (DIM / 4) + lane];
    }
    f32x4 r = (a0 + a1) + (a2 + a3);
    r *= SCALE;
    f32x4* dst = (f32x4*)(out + (size_t)b * (KSEL + 1) * DIM +
                          (size_t)KSEL * DIM);
    dst[lane] = r;
  }
}

extern "C" void kernel_launch(void* const* d_in, const int* in_sizes, int n_in,
                              void* d_out, int out_size, void* d_ws, size_t ws_size,
                              hipStream_t stream) {
  (void)in_sizes; (void)n_in; (void)out_size; (void)ws_size;
  const float* seq = (const float*)d_in[0];
  const float* w   = (const float*)d_in[1];
  float* out = (float*)d_out;

  // workspace layout: rank-per-token | partial sums | fan-in counters
  int* rk = (int*)d_ws;                           // BATCH*NTOK ints (256 KB)
  float* part = (float*)(rk + BATCH * NTOK);      // BATCH*GBLK*DIM f32 (8 MB)
  unsigned int* cnt = (unsigned int*)(part + (size_t)BATCH * GBLK * DIM);

  rank_kernel<<<dim3(RBLK, BATCH), RTHREADS, 0, stream>>>(w, rk, cnt);
  gather_kernel<<<dim3(GBLK, BATCH), 256, 0, stream>>>(seq, rk, out, part, cnt);
}

// Round 7
// 403.750 us; speedup vs baseline: 1.6922x; 1.6922x over previous
//
#include <hip/hip_runtime.h>

// Problem constants (fixed by reference: seq (16,4096,1024) fp32, prune 0.5)
#define BATCH 16
#define NTOK  4096
#define DIM   1024
#define KSEL  2048                       // kept tokens
#define NPRUNE 2048                      // pruned tokens

#define NBIN 4096                        // 12-bit counting-sort bins
#define RTHREADS 1024
#define RBLK 4                           // rank blocks per batch
#define TPT (NTOK / RTHREADS)            // 4 tokens/thread (hist/scatter)
#define BPT (NBIN / RTHREADS)            // 4 bins/thread (scan)

#define GROWS 32                         // rows per gather block (128 KB)
#define GBLK (NTOK / GROWS)              // 128 gather blocks per batch

typedef __attribute__((ext_vector_type(4))) float f32x4;

// ---------------------------------------------------------------------------
// MEASURED-BEST STRUCTURE (r2, 404.9 us). Post-mortems of all deviations:
//  r3 fused rank-into-gather: +7 us (re-introduced O(N^2) compares).
//  r4 atomicAdd mixup row:    +18 us (2M device-scope data atomics serialize).
//  r5 fan-in + __threadfence: +278 us (device-scope fence after streaming
//     stores = per-block L2 writeback; gather 63 -> 384 us at 9% BW).
// Do not add device-scope fences/atomics to the gather's hot path.
// (r6 bench attempt of this exact source failed on container acquisition —
//  resubmitted unchanged.)
// ---------------------------------------------------------------------------

// ---------------------------------------------------------------------------
// Kernel 1: counting-sort rank -> rk[b][token] = rank.
// key(i) = (~sortable(w_i) << 32) | i  — ascending u64 order == jax.lax.top_k
// order (value desc, index asc). bin = top 12 bits. rank = bin base + exact
// within-bin count. grid (RBLK, BATCH): each block builds the full per-batch
// histogram/scan/scatter (O(N), duplicated, cheap) but ranks only a quarter
// of the tokens (1 token/thread).
// ---------------------------------------------------------------------------
__global__ __launch_bounds__(1024) void rank_kernel(
    const float* __restrict__ w, int* __restrict__ rk) {
  __shared__ unsigned int s_cnt[NBIN];            // 16 KB histogram
  __shared__ unsigned int s_base[NBIN];           // 16 KB excl-scan bases
  __shared__ unsigned int s_cur[NBIN];            // 16 KB scatter cursors
  __shared__ unsigned long long s_key[NTOK];      // 32 KB keys grouped by bin
  __shared__ unsigned int s_wsum[16];
  __shared__ unsigned int s_woff[16];

  const int b = blockIdx.y;
  const int qq = blockIdx.x;                      // token quarter to rank
  const int t = threadIdx.x;
  const float* wb = w + (size_t)b * NTOK;

  for (int i = t; i < NBIN; i += RTHREADS) s_cnt[i] = 0;
  __syncthreads();

  // load, keyify, histogram (all tokens of the batch)
  unsigned int inv[TPT];
  unsigned int bin[TPT];
#pragma unroll
  for (int p = 0; p < TPT; ++p) {
    const int j = p * RTHREADS + t;
    const unsigned int u = __float_as_uint(wb[j]);
    const unsigned int s = (u & 0x80000000u) ? ~u : (u | 0x80000000u);
    const unsigned int iv = ~s;                   // ascending iv == desc value
    inv[p] = iv; bin[p] = iv >> 20;
    atomicAdd(&s_cnt[bin[p]], 1u);
  }
  __syncthreads();

  // exclusive scan over 4096 bins: 4 bins/thread -> wave shfl scan -> combine
  unsigned int c[BPT];
  unsigned int lsum = 0;
#pragma unroll
  for (int i = 0; i < BPT; ++i) { c[i] = s_cnt[t * BPT + i]; lsum += c[i]; }
  const int lane = t & 63, wid = t >> 6;
  unsigned int v = lsum;
  for (int d = 1; d < 64; d <<= 1) {
    unsigned int up = __shfl_up(v, d, 64);
    if (lane >= d) v += up;
  }
  if (lane == 63) s_wsum[wid] = v;
  __syncthreads();
  if (t == 0) {
    unsigned int run = 0;
    for (int i = 0; i < 16; ++i) { const unsigned int x = s_wsum[i]; s_woff[i] = run; run += x; }
  }
  __syncthreads();
  unsigned int excl = v - lsum + s_woff[wid];
#pragma unroll
  for (int i = 0; i < BPT; ++i) {
    s_base[t * BPT + i] = excl;
    s_cur[t * BPT + i] = excl;
    excl += c[i];
  }
  __syncthreads();

  // scatter keys grouped by bin (arbitrary order within bin; rank is exact)
#pragma unroll
  for (int p = 0; p < TPT; ++p) {
    const int j = p * RTHREADS + t;
    const unsigned long long key =
        ((unsigned long long)inv[p] << 32) | (unsigned int)j;
    const unsigned int pos = atomicAdd(&s_cur[bin[p]], 1u);
    s_key[pos] = key;
  }
  __syncthreads();

  // exact rank for this block's quarter: 1 token/thread
  const int tok = qq * RTHREADS + t;
  const unsigned int u = __float_as_uint(wb[tok]);   // L1-hot reload
  const unsigned int s = (u & 0x80000000u) ? ~u : (u | 0x80000000u);
  const unsigned int iv = ~s;
  const unsigned long long key =
      ((unsigned long long)iv << 32) | (unsigned int)tok;
  const unsigned int bb = iv >> 20;
  const unsigned int st = s_base[bb];
  const unsigned int en = s_cur[bb];              // base + count
  unsigned int r = st;
  for (unsigned int q = st; q < en; ++q) r += (s_key[q] < key);
  rk[b * NTOK + tok] = (int)r;
}

// ---------------------------------------------------------------------------
// Kernel 2: streaming gather. Reads seq PERFECTLY SEQUENTIALLY (each block:
// 32 consecutive rows = 128 KB, nontemporal), scatter-writes kept rows to
// out[rank] (4 KB scattered writes are fire-and-forget), accumulates pruned
// rows in-register, plain-stores one partial row per block (cached; reduce
// kernel reads it). NO fences, NO atomics in this kernel (see post-mortems).
// grid (GBLK, BATCH), block = 256 (1 f32x4/lane).
// ---------------------------------------------------------------------------
__global__ __launch_bounds__(256) void gather_kernel(
    const float* __restrict__ seq, const int* __restrict__ rk,
    float* __restrict__ out, float* __restrict__ part) {
  const int b = blockIdx.y, g = blockIdx.x;
  const int lane = threadIdx.x;
  const f32x4* src = (const f32x4*)(seq + (size_t)b * NTOK * DIM) +
                     (size_t)g * GROWS * (DIM / 4);
  const int* rkb = rk + b * NTOK + g * GROWS;
  f32x4* outb = (f32x4*)(out + (size_t)b * (KSEL + 1) * DIM);
  f32x4 acc = {0.f, 0.f, 0.f, 0.f};
#pragma unroll 8
  for (int i = 0; i < GROWS; ++i) {
    const f32x4 x = __builtin_nontemporal_load(src + (size_t)i * (DIM / 4) + lane);
    const int r = rkb[i];                          // uniform -> scalar load
    if (r < KSEL) {
      __builtin_nontemporal_store(x, outb + (size_t)r * (DIM / 4) + lane);
    } else {
      acc += x;
    }
  }
  f32x4* pdst = (f32x4*)(part + ((size_t)b * GBLK + g) * DIM);
  pdst[lane] = acc;                                // plain store: stays cached
}

// ---------------------------------------------------------------------------
// Kernel 3: reduce GBLK partials per batch, scale, write out row KSEL.
// grid (4, BATCH): each block owns a quarter of DIM; 4 thread-groups sum
// 32 chunks each, combine through LDS.
// ---------------------------------------------------------------------------
__global__ __launch_bounds__(256) void reduce_kernel(
    const float* __restrict__ part, float* __restrict__ out, float scale) {
  __shared__ f32x4 s_acc[4][64];
  const int b = blockIdx.y, qq = blockIdx.x;
  const int t = threadIdx.x, g = t >> 6, col = t & 63;
  const int c4 = qq * 64 + col;                    // float4 column in [0,256)
  const f32x4* p = (const f32x4*)(part + (size_t)b * GBLK * DIM);
  f32x4 acc = {0.f, 0.f, 0.f, 0.f};
#pragma unroll
  for (int i = 0; i < GBLK / 4; ++i) {
    const int ch = g + 4 * i;
    acc += p[(size_t)ch * (DIM / 4) + c4];
  }
  s_acc[g][col] = acc;
  __syncthreads();
  if (g == 0) {
    f32x4 r = (s_acc[0][col] + s_acc[1][col]) + (s_acc[2][col] + s_acc[3][col]);
    r *= scale;
    f32x4* dst = (f32x4*)(out + (size_t)b * (KSEL + 1) * DIM +
                          (size_t)KSEL * DIM);
    dst[c4] = r;
  }
}

extern "C" void kernel_launch(void* const* d_in, const int* in_sizes, int n_in,
                              void* d_out, int out_size, void* d_ws, size_t ws_size,
                              hipStream_t stream) {
  (void)in_sizes; (void)n_in; (void)out_size; (void)ws_size;
  const float* seq = (const float*)d_in[0];
  const float* w   = (const float*)d_in[1];
  float* out = (float*)d_out;

  // workspace layout: rank-per-token | partial sums
  int* rk = (int*)d_ws;                          // BATCH*NTOK ints (256 KB)
  float* part = (float*)(rk + BATCH * NTOK);     // BATCH*GBLK*DIM floats (8 MB)

  rank_kernel<<<dim3(RBLK, BATCH), RTHREADS, 0, stream>>>(w, rk);
  gather_kernel<<<dim3(GBLK, BATCH), 256, 0, stream>>>(seq, rk, out, part);
  const float scale = (float)(0.05 / (2048.0 + 1e-10));
  reduce_kernel<<<dim3(4, BATCH), 256, 0, stream>>>(part, out, scale);
}